// Round 1
// baseline (1471.886 us; speedup 1.0000x reference)
//
#include <hip/hip_runtime.h>

#define NN 50000
#define EE 1600000

static __device__ __forceinline__ float4 f4z() { return make_float4(0.f, 0.f, 0.f, 0.f); }

// ---------------- CSR build ----------------

__global__ __launch_bounds__(256) void hist_kernel(const int* __restrict__ ei, int* __restrict__ counts)
{
    int i = blockIdx.x * blockDim.x + threadIdx.x;
    int stride = gridDim.x * blockDim.x;
    for (; i < EE; i += stride) atomicAdd(&counts[ei[EE + i]], 1);
}

__global__ __launch_bounds__(1024) void scan_kernel(const int* __restrict__ counts,
                                                    int* __restrict__ offsets,
                                                    int* __restrict__ cursor)
{
    __shared__ int buf[1024];
    const int t = threadIdx.x;
    const int M = 49;                      // 1024*49 = 50176 >= 50001
    const int base = t * M;
    int s = 0;
    for (int j = 0; j < M; ++j) { int i = base + j; if (i < NN) s += counts[i]; }
    buf[t] = s;
    __syncthreads();
    for (int ofs = 1; ofs < 1024; ofs <<= 1) {
        int add = (t >= ofs) ? buf[t - ofs] : 0;
        __syncthreads();
        buf[t] += add;
        __syncthreads();
    }
    int run = buf[t] - s;                  // exclusive prefix of this thread's chunk
    for (int j = 0; j < M; ++j) {
        int i = base + j;
        if (i < NN) { offsets[i] = run; cursor[i] = run; run += counts[i]; }
        else if (i == NN) { offsets[NN] = run; }
    }
}

__global__ __launch_bounds__(256) void scatter_kernel(const int* __restrict__ ei,
                                                      int* __restrict__ cursor,
                                                      int* __restrict__ sorted)
{
    int i = blockIdx.x * blockDim.x + threadIdx.x;
    int stride = gridDim.x * blockDim.x;
    for (; i < EE; i += stride) {
        int d = ei[EE + i];
        int pos = atomicAdd(&cursor[d], 1);
        sorted[pos] = i;
    }
}

// ---------------- fused q/k/v/xr projection ----------------
// block: 256 threads, 32 rows x 128 cols x 4 matrices. x tile staged in LDS.

__global__ __launch_bounds__(256) void proj_kernel(
    const float* __restrict__ x,
    const float* __restrict__ Wq, const float* __restrict__ bq,
    const float* __restrict__ Wk, const float* __restrict__ bk,
    const float* __restrict__ Wv, const float* __restrict__ bv,
    const float* __restrict__ Ws, const float* __restrict__ bs,
    float* __restrict__ q, float* __restrict__ k,
    float* __restrict__ v, float* __restrict__ xr)
{
    __shared__ float xs[32][128];
    const int tid = threadIdx.x;
    const int row0 = blockIdx.x * 32;
    for (int i = tid; i < 1024; i += 256) {
        int r = i >> 5, c4 = i & 31;
        int gr = row0 + r;
        float4 val = f4z();
        if (gr < NN) val = ((const float4*)(x + (size_t)gr * 128))[c4];
        ((float4*)xs[r])[c4] = val;
    }
    __syncthreads();
    const int cg = tid & 31;   // cols 4cg..4cg+3
    const int rg = tid >> 5;   // rows 4rg..4rg+3
    float4 aq[4], ak[4], av[4], as_[4];
    #pragma unroll
    for (int r = 0; r < 4; ++r) { aq[r] = f4z(); ak[r] = f4z(); av[r] = f4z(); as_[r] = f4z(); }
    #pragma unroll 2
    for (int kk = 0; kk < 128; ++kk) {
        float4 wq = ((const float4*)(Wq + kk * 128))[cg];
        float4 wk = ((const float4*)(Wk + kk * 128))[cg];
        float4 wv = ((const float4*)(Wv + kk * 128))[cg];
        float4 ws = ((const float4*)(Ws + kk * 128))[cg];
        #pragma unroll
        for (int r = 0; r < 4; ++r) {
            float xv = xs[4 * rg + r][kk];
            aq[r].x += xv * wq.x; aq[r].y += xv * wq.y; aq[r].z += xv * wq.z; aq[r].w += xv * wq.w;
            ak[r].x += xv * wk.x; ak[r].y += xv * wk.y; ak[r].z += xv * wk.z; ak[r].w += xv * wk.w;
            av[r].x += xv * wv.x; av[r].y += xv * wv.y; av[r].z += xv * wv.z; av[r].w += xv * wv.w;
            as_[r].x += xv * ws.x; as_[r].y += xv * ws.y; as_[r].z += xv * ws.z; as_[r].w += xv * ws.w;
        }
    }
    const float4 bq4 = ((const float4*)bq)[cg];
    const float4 bk4 = ((const float4*)bk)[cg];
    const float4 bv4 = ((const float4*)bv)[cg];
    const float4 bs4 = ((const float4*)bs)[cg];
    #pragma unroll
    for (int r = 0; r < 4; ++r) {
        int gr = row0 + 4 * rg + r;
        if (gr >= NN) continue;
        float4 o;
        o.x = aq[r].x + bq4.x; o.y = aq[r].y + bq4.y; o.z = aq[r].z + bq4.z; o.w = aq[r].w + bq4.w;
        ((float4*)(q + (size_t)gr * 128))[cg] = o;
        o.x = ak[r].x + bk4.x; o.y = ak[r].y + bk4.y; o.z = ak[r].z + bk4.z; o.w = ak[r].w + bk4.w;
        ((float4*)(k + (size_t)gr * 128))[cg] = o;
        o.x = av[r].x + bv4.x; o.y = av[r].y + bv4.y; o.z = av[r].z + bv4.z; o.w = av[r].w + bv4.w;
        ((float4*)(v + (size_t)gr * 128))[cg] = o;
        o.x = as_[r].x + bs4.x; o.y = as_[r].y + bs4.y; o.z = as_[r].z + bs4.z; o.w = as_[r].w + bs4.w;
        ((float4*)(xr + (size_t)gr * 128))[cg] = o;
    }
}

// ---------------- fused attention + beta-skip + LN1 + relu ----------------
// one wave per dst node, CSR edge list; We columns register-resident.

__global__ __launch_bounds__(256) void attn_kernel(
    const int* __restrict__ ei, const float* __restrict__ efeat,
    const float* __restrict__ We, const float* __restrict__ be,
    const float* __restrict__ q, const float* __restrict__ k, const float* __restrict__ v,
    const float* __restrict__ xr, const float* __restrict__ x,
    const float* __restrict__ Wbeta,
    const float* __restrict__ ln1g, const float* __restrict__ ln1b,
    const int* __restrict__ offsets, const int* __restrict__ sorted,
    float* __restrict__ h, float* __restrict__ colsum)
{
    const int lane = threadIdx.x & 63;
    const int wid = threadIdx.x >> 6;
    const int gwave = blockIdx.x * 4 + wid;
    const int nwave = gridDim.x * 4;
    const int f0 = 2 * lane;

    float we0[32], we1[32];
    #pragma unroll
    for (int d = 0; d < 32; ++d) {
        float2 w2 = *(const float2*)(We + d * 128 + f0);
        we0[d] = w2.x; we1[d] = w2.y;
    }
    const float be0 = be[f0], be1 = be[f0 + 1];
    const float wbo0 = Wbeta[f0],       wbo1 = Wbeta[f0 + 1];
    const float wbr0 = Wbeta[128 + f0], wbr1 = Wbeta[128 + f0 + 1];
    const float wbd0 = Wbeta[256 + f0], wbd1 = Wbeta[256 + f0 + 1];
    const float lg0 = ln1g[f0], lg1 = ln1g[f0 + 1];
    const float lb0 = ln1b[f0], lb1 = ln1b[f0 + 1];

    __shared__ float cs[4][128];
    cs[wid][f0] = 0.f; cs[wid][f0 + 1] = 0.f;

    for (int node = gwave; node < NN; node += nwave) {
        const int beg = offsets[node];
        const int end = offsets[node + 1];
        const float2 qv = *(const float2*)(q + (size_t)node * 128 + f0);
        float m = -1e30f, s = 0.f, acc0 = 0.f, acc1 = 0.f;
        for (int t = beg; t < end; ++t) {
            const int eid = sorted[t];
            const int src = ei[eid];
            const float4* ef4 = (const float4*)(efeat + (size_t)eid * 32);
            float e0a = be0, e0b = 0.f, e1a = be1, e1b = 0.f;
            float4 efv[4];
            #pragma unroll
            for (int c = 0; c < 4; ++c) efv[c] = ef4[c];
            #pragma unroll
            for (int c = 0; c < 4; ++c) {
                e0a += efv[c].x * we0[4 * c + 0]; e1a += efv[c].x * we1[4 * c + 0];
                e0b += efv[c].y * we0[4 * c + 1]; e1b += efv[c].y * we1[4 * c + 1];
                e0a += efv[c].z * we0[4 * c + 2]; e1a += efv[c].z * we1[4 * c + 2];
                e0b += efv[c].w * we0[4 * c + 3]; e1b += efv[c].w * we1[4 * c + 3];
            }
            #pragma unroll
            for (int c = 0; c < 4; ++c) efv[c] = ef4[4 + c];
            #pragma unroll
            for (int c = 0; c < 4; ++c) {
                e0a += efv[c].x * we0[16 + 4 * c + 0]; e1a += efv[c].x * we1[16 + 4 * c + 0];
                e0b += efv[c].y * we0[16 + 4 * c + 1]; e1b += efv[c].y * we1[16 + 4 * c + 1];
                e0a += efv[c].z * we0[16 + 4 * c + 2]; e1a += efv[c].z * we1[16 + 4 * c + 2];
                e0b += efv[c].w * we0[16 + 4 * c + 3]; e1b += efv[c].w * we1[16 + 4 * c + 3];
            }
            const float e0 = e0a + e0b, e1 = e1a + e1b;
            const float2 kv = *(const float2*)(k + (size_t)src * 128 + f0);
            float part = qv.x * (kv.x + e0) + qv.y * (kv.y + e1);
            part += __shfl_xor(part, 1);
            part += __shfl_xor(part, 2);
            part += __shfl_xor(part, 4);        // 8-lane head group
            const float logit = part * 0.25f;   // / sqrt(16)
            const float nm = fmaxf(m, logit);
            const float scale = __expf(m - nm);
            const float p = __expf(logit - nm);
            const float2 vv = *(const float2*)(v + (size_t)src * 128 + f0);
            s = s * scale + p;
            acc0 = acc0 * scale + p * (vv.x + e0);
            acc1 = acc1 * scale + p * (vv.y + e1);
            m = nm;
        }
        const float inv = 1.f / (s + 1e-16f);
        const float o0 = acc0 * inv, o1 = acc1 * inv;
        const float2 xrv = *(const float2*)(xr + (size_t)node * 128 + f0);
        float bp = o0 * wbo0 + o1 * wbo1 + xrv.x * wbr0 + xrv.y * wbr1
                 + (o0 - xrv.x) * wbd0 + (o1 - xrv.y) * wbd1;
        #pragma unroll
        for (int msk = 1; msk < 64; msk <<= 1) bp += __shfl_xor(bp, msk);
        const float beta = 1.f / (1.f + __expf(-bp));
        const float2 xv = *(const float2*)(x + (size_t)node * 128 + f0);
        float t0 = beta * xrv.x + (1.f - beta) * o0 + xv.x;
        float t1 = beta * xrv.y + (1.f - beta) * o1 + xv.y;
        float sm = t0 + t1, sq = t0 * t0 + t1 * t1;
        #pragma unroll
        for (int msk = 1; msk < 64; msk <<= 1) { sm += __shfl_xor(sm, msk); sq += __shfl_xor(sq, msk); }
        const float mu = sm * (1.f / 128.f);
        const float var = sq * (1.f / 128.f) - mu * mu;
        const float rstd = rsqrtf(var + 1e-5f);
        const float h0 = fmaxf((t0 - mu) * rstd * lg0 + lb0, 0.f);
        const float h1 = fmaxf((t1 - mu) * rstd * lg1 + lb1, 0.f);
        *(float2*)(h + (size_t)node * 128 + f0) = make_float2(h0, h1);
        cs[wid][f0] += h0; cs[wid][f0 + 1] += h1;
    }
    __syncthreads();
    if (wid == 0) {
        float c0 = cs[0][f0] + cs[1][f0] + cs[2][f0] + cs[3][f0];
        float c1 = cs[0][f0 + 1] + cs[1][f0 + 1] + cs[2][f0 + 1] + cs[3][f0 + 1];
        atomicAdd(&colsum[f0], c0);
        atomicAdd(&colsum[f0 + 1], c1);
    }
}

// ---------------- global context (tiny) ----------------
// gc[0:128] = g_bc ; gc[128:256] = c2 = bg + g_bc @ Wg[128:256,:]

__global__ __launch_bounds__(128) void gctx_kernel(
    const float* __restrict__ colsum,
    const float* __restrict__ Wr, const float* __restrict__ br,
    const float* __restrict__ Ww, const float* __restrict__ bw,
    const float* __restrict__ Wg, const float* __restrict__ bg,
    float* __restrict__ gc)
{
    __shared__ float hm[128], g[128], gb[128];
    const int f = threadIdx.x;
    hm[f] = colsum[f] * (1.f / (float)NN);
    __syncthreads();
    float a = br[f];
    for (int i = 0; i < 128; ++i) a += hm[i] * Wr[i * 128 + f];
    g[f] = fmaxf(a, 0.f);
    __syncthreads();
    float b = bw[f];
    for (int i = 0; i < 128; ++i) b += g[i] * Ww[i * 128 + f];
    gb[f] = b;
    gc[f] = b;
    __syncthreads();
    float c = bg[f];
    for (int i = 0; i < 128; ++i) c += gb[i] * Wg[(128 + i) * 128 + f];
    gc[128 + f] = c;
}

// ---------------- final: h@Wg[:128] + gate + LN2 fused ----------------

__global__ __launch_bounds__(256) void final_kernel(
    const float* __restrict__ h, const float* __restrict__ Wg,
    const float* __restrict__ gc,
    const float* __restrict__ ln2g, const float* __restrict__ ln2b,
    float* __restrict__ out)
{
    __shared__ float hs[32][128];
    __shared__ float ys[32][128];
    const int tid = threadIdx.x;
    const int row0 = blockIdx.x * 32;
    for (int i = tid; i < 1024; i += 256) {
        int r = i >> 5, c4 = i & 31;
        int gr = row0 + r;
        float4 val = f4z();
        if (gr < NN) val = ((const float4*)(h + (size_t)gr * 128))[c4];
        ((float4*)hs[r])[c4] = val;
    }
    __syncthreads();
    const int cg = tid & 31;
    const int rg = tid >> 5;
    float4 a[4];
    #pragma unroll
    for (int r = 0; r < 4; ++r) a[r] = f4z();
    #pragma unroll 2
    for (int kk = 0; kk < 128; ++kk) {
        float4 w4 = ((const float4*)(Wg + kk * 128))[cg];
        #pragma unroll
        for (int r = 0; r < 4; ++r) {
            float xv = hs[4 * rg + r][kk];
            a[r].x += xv * w4.x; a[r].y += xv * w4.y; a[r].z += xv * w4.z; a[r].w += xv * w4.w;
        }
    }
    const float4 gb = ((const float4*)gc)[cg];
    const float4 c2 = ((const float4*)(gc + 128))[cg];
    #pragma unroll
    for (int r = 0; r < 4; ++r) {
        int row = 4 * rg + r;
        float4 hv = ((float4*)hs[row])[cg];
        float4 y;
        float gx;
        gx = 1.f / (1.f + __expf(-(a[r].x + c2.x))); y.x = hv.x + gx * gb.x;
        gx = 1.f / (1.f + __expf(-(a[r].y + c2.y))); y.y = hv.y + gx * gb.y;
        gx = 1.f / (1.f + __expf(-(a[r].z + c2.z))); y.z = hv.z + gx * gb.z;
        gx = 1.f / (1.f + __expf(-(a[r].w + c2.w))); y.w = hv.w + gx * gb.w;
        ((float4*)ys[row])[cg] = y;
    }
    __syncthreads();
    const int lane = tid & 63;
    const int wid = tid >> 6;
    const int f0 = 2 * lane;
    const float lg0 = ln2g[f0], lg1 = ln2g[f0 + 1];
    const float lb0 = ln2b[f0], lb1 = ln2b[f0 + 1];
    for (int rr = 0; rr < 8; ++rr) {
        int row = wid * 8 + rr;
        int gr = row0 + row;
        if (gr >= NN) continue;
        float y0 = ys[row][f0], y1 = ys[row][f0 + 1];
        float sm = y0 + y1, sq = y0 * y0 + y1 * y1;
        #pragma unroll
        for (int msk = 1; msk < 64; msk <<= 1) { sm += __shfl_xor(sm, msk); sq += __shfl_xor(sq, msk); }
        float mu = sm * (1.f / 128.f);
        float var = sq * (1.f / 128.f) - mu * mu;
        float rstd = rsqrtf(var + 1e-5f);
        float o0 = (y0 - mu) * rstd * lg0 + lb0;
        float o1 = (y1 - mu) * rstd * lg1 + lb1;
        *(float2*)(out + (size_t)gr * 128 + f0) = make_float2(o0, o1);
    }
}

// ---------------- launch ----------------

extern "C" void kernel_launch(void* const* d_in, const int* in_sizes, int n_in,
                              void* d_out, int out_size, void* d_ws, size_t ws_size,
                              hipStream_t stream)
{
    const float* x    = (const float*)d_in[0];
    const int*   ei   = (const int*)d_in[1];
    const float* ef   = (const float*)d_in[2];
    const float* Wq   = (const float*)d_in[3];
    const float* bq   = (const float*)d_in[4];
    const float* Wk   = (const float*)d_in[5];
    const float* bk   = (const float*)d_in[6];
    const float* Wv   = (const float*)d_in[7];
    const float* bv   = (const float*)d_in[8];
    const float* We   = (const float*)d_in[9];
    const float* be   = (const float*)d_in[10];
    const float* Wsk  = (const float*)d_in[11];
    const float* bsk  = (const float*)d_in[12];
    const float* Wbeta= (const float*)d_in[13];
    const float* g1   = (const float*)d_in[14];
    const float* b1   = (const float*)d_in[15];
    const float* Wr   = (const float*)d_in[16];
    const float* br   = (const float*)d_in[17];
    const float* Ww   = (const float*)d_in[18];
    const float* bw   = (const float*)d_in[19];
    const float* Wg   = (const float*)d_in[20];
    const float* bg   = (const float*)d_in[21];
    const float* g2   = (const float*)d_in[22];
    const float* b2   = (const float*)d_in[23];
    float* out = (float*)d_out;

    const size_t NF = (size_t)NN * 128;
    float* q      = (float*)d_ws;
    float* k      = q + NF;
    float* v      = k + NF;
    float* xr     = v + NF;
    float* h      = xr + NF;
    float* colsum = h + NF;
    float* gc     = colsum + 128;            // 256 floats
    int* counts   = (int*)(gc + 256);
    int* offsets  = counts + NN;             // NN+1
    int* cursor   = offsets + NN + 1;
    int* sorted   = cursor + NN;             // EE

    hipMemsetAsync(counts, 0, NN * sizeof(int), stream);
    hipMemsetAsync(colsum, 0, 128 * sizeof(float), stream);

    hist_kernel<<<2048, 256, 0, stream>>>(ei, counts);
    scan_kernel<<<1, 1024, 0, stream>>>(counts, offsets, cursor);
    scatter_kernel<<<2048, 256, 0, stream>>>(ei, cursor, sorted);
    proj_kernel<<<(NN + 31) / 32, 256, 0, stream>>>(x, Wq, bq, Wk, bk, Wv, bv, Wsk, bsk, q, k, v, xr);
    attn_kernel<<<2048, 256, 0, stream>>>(ei, ef, We, be, q, k, v, xr, x, Wbeta, g1, b1,
                                          offsets, sorted, h, colsum);
    gctx_kernel<<<1, 128, 0, stream>>>(colsum, Wr, br, Ww, bw, Wg, bg, gc);
    final_kernel<<<(NN + 31) / 32, 256, 0, stream>>>(h, Wg, gc, g2, b2, out);
}

// Round 2
// 1012.253 us; speedup vs baseline: 1.4541x; 1.4541x over previous
//
#include <hip/hip_runtime.h>

#define NN 50000
#define EE 1600000

static __device__ __forceinline__ float4 f4z() { return make_float4(0.f, 0.f, 0.f, 0.f); }

// ---------------- CSR build ----------------

__global__ __launch_bounds__(256) void hist_kernel(const int* __restrict__ ei, int* __restrict__ counts)
{
    int i = blockIdx.x * blockDim.x + threadIdx.x;
    int stride = gridDim.x * blockDim.x;
    for (; i < EE; i += stride) atomicAdd(&counts[ei[EE + i]], 1);
}

__global__ __launch_bounds__(1024) void scan_kernel(const int* __restrict__ counts,
                                                    int* __restrict__ offsets,
                                                    int* __restrict__ cursor)
{
    __shared__ int buf[1024];
    const int t = threadIdx.x;
    const int M = 49;                      // 1024*49 = 50176 >= 50001
    const int base = t * M;
    int s = 0;
    for (int j = 0; j < M; ++j) { int i = base + j; if (i < NN) s += counts[i]; }
    buf[t] = s;
    __syncthreads();
    for (int ofs = 1; ofs < 1024; ofs <<= 1) {
        int add = (t >= ofs) ? buf[t - ofs] : 0;
        __syncthreads();
        buf[t] += add;
        __syncthreads();
    }
    int run = buf[t] - s;
    for (int j = 0; j < M; ++j) {
        int i = base + j;
        if (i < NN) { offsets[i] = run; cursor[i] = run; run += counts[i]; }
        else if (i == NN) { offsets[NN] = run; }
    }
}

__global__ __launch_bounds__(256) void scatter_kernel(const int* __restrict__ ei,
                                                      int* __restrict__ cursor,
                                                      int2* __restrict__ sorted2)
{
    int i = blockIdx.x * blockDim.x + threadIdx.x;
    int stride = gridDim.x * blockDim.x;
    for (; i < EE; i += stride) {
        int srcn = ei[i];
        int d = ei[EE + i];
        int pos = atomicAdd(&cursor[d], 1);
        sorted2[pos] = make_int2(i, srcn);
    }
}

// ---------------- fused q/k/v/xr projection ----------------

__global__ __launch_bounds__(256) void proj_kernel(
    const float* __restrict__ x,
    const float* __restrict__ Wq, const float* __restrict__ bq,
    const float* __restrict__ Wk, const float* __restrict__ bk,
    const float* __restrict__ Wv, const float* __restrict__ bv,
    const float* __restrict__ Ws, const float* __restrict__ bs,
    float* __restrict__ q, float* __restrict__ k,
    float* __restrict__ v, float* __restrict__ xr)
{
    __shared__ float xs[32][128];
    const int tid = threadIdx.x;
    const int row0 = blockIdx.x * 32;
    for (int i = tid; i < 1024; i += 256) {
        int r = i >> 5, c4 = i & 31;
        int gr = row0 + r;
        float4 val = f4z();
        if (gr < NN) val = ((const float4*)(x + (size_t)gr * 128))[c4];
        ((float4*)xs[r])[c4] = val;
    }
    __syncthreads();
    const int cg = tid & 31;
    const int rg = tid >> 5;
    float4 aq[4], ak[4], av[4], as_[4];
    #pragma unroll
    for (int r = 0; r < 4; ++r) { aq[r] = f4z(); ak[r] = f4z(); av[r] = f4z(); as_[r] = f4z(); }
    #pragma unroll 2
    for (int kk = 0; kk < 128; ++kk) {
        float4 wq = ((const float4*)(Wq + kk * 128))[cg];
        float4 wk = ((const float4*)(Wk + kk * 128))[cg];
        float4 wv = ((const float4*)(Wv + kk * 128))[cg];
        float4 ws = ((const float4*)(Ws + kk * 128))[cg];
        #pragma unroll
        for (int r = 0; r < 4; ++r) {
            float xv = xs[4 * rg + r][kk];
            aq[r].x += xv * wq.x; aq[r].y += xv * wq.y; aq[r].z += xv * wq.z; aq[r].w += xv * wq.w;
            ak[r].x += xv * wk.x; ak[r].y += xv * wk.y; ak[r].z += xv * wk.z; ak[r].w += xv * wk.w;
            av[r].x += xv * wv.x; av[r].y += xv * wv.y; av[r].z += xv * wv.z; av[r].w += xv * wv.w;
            as_[r].x += xv * ws.x; as_[r].y += xv * ws.y; as_[r].z += xv * ws.z; as_[r].w += xv * ws.w;
        }
    }
    const float4 bq4 = ((const float4*)bq)[cg];
    const float4 bk4 = ((const float4*)bk)[cg];
    const float4 bv4 = ((const float4*)bv)[cg];
    const float4 bs4 = ((const float4*)bs)[cg];
    #pragma unroll
    for (int r = 0; r < 4; ++r) {
        int gr = row0 + 4 * rg + r;
        if (gr >= NN) continue;
        float4 o;
        o.x = aq[r].x + bq4.x; o.y = aq[r].y + bq4.y; o.z = aq[r].z + bq4.z; o.w = aq[r].w + bq4.w;
        ((float4*)(q + (size_t)gr * 128))[cg] = o;
        o.x = ak[r].x + bk4.x; o.y = ak[r].y + bk4.y; o.z = ak[r].z + bk4.z; o.w = ak[r].w + bk4.w;
        ((float4*)(k + (size_t)gr * 128))[cg] = o;
        o.x = av[r].x + bv4.x; o.y = av[r].y + bv4.y; o.z = av[r].z + bv4.z; o.w = av[r].w + bv4.w;
        ((float4*)(v + (size_t)gr * 128))[cg] = o;
        o.x = as_[r].x + bs4.x; o.y = as_[r].y + bs4.y; o.z = as_[r].z + bs4.z; o.w = as_[r].w + bs4.w;
        ((float4*)(xr + (size_t)gr * 128))[cg] = o;
    }
}

// ---------------- Wqe expansion: Wqe[f][h*32+d] = We[d][f] if f in head h ----------------

__global__ __launch_bounds__(256) void build_wqe(const float* __restrict__ We, float* __restrict__ Wqe)
{
    int idx = blockIdx.x * 256 + threadIdx.x;      // 128*256 = 32768
    if (idx >= 128 * 256) return;
    int f = idx >> 8, c = idx & 255, hh = c >> 5, d = c & 31;
    Wqe[idx] = ((f >> 4) == hh) ? We[d * 128 + f] : 0.f;
}

// ---------------- qe = q @ Wqe  [N,256] ----------------

__global__ __launch_bounds__(256) void qe_kernel(const float* __restrict__ q,
                                                 const float* __restrict__ Wqe,
                                                 float* __restrict__ qe)
{
    __shared__ float xs[16][128];
    const int tid = threadIdx.x;
    const int row0 = blockIdx.x * 16;
    for (int i = tid; i < 512; i += 256) {
        int r = i >> 5, c4 = i & 31;
        int gr = row0 + r;
        float4 val = f4z();
        if (gr < NN) val = ((const float4*)(q + (size_t)gr * 128))[c4];
        ((float4*)xs[r])[c4] = val;
    }
    __syncthreads();
    const int cg = tid & 63;        // 4 cols each over 256
    const int rg = tid >> 6;        // 4 rows each over 16
    float4 a[4];
    #pragma unroll
    for (int r = 0; r < 4; ++r) a[r] = f4z();
    #pragma unroll 2
    for (int kk = 0; kk < 128; ++kk) {
        float4 w4 = ((const float4*)(Wqe + kk * 256))[cg];
        #pragma unroll
        for (int r = 0; r < 4; ++r) {
            float xv = xs[4 * rg + r][kk];
            a[r].x += xv * w4.x; a[r].y += xv * w4.y; a[r].z += xv * w4.z; a[r].w += xv * w4.w;
        }
    }
    #pragma unroll
    for (int r = 0; r < 4; ++r) {
        int gr = row0 + 4 * rg + r;
        if (gr < NN) ((float4*)(qe + (size_t)gr * 256))[cg] = a[r];
    }
}

// ---------------- fused attention + beta-skip + LN1 + relu ----------------
// one wave per dst node; per-edge cost: 1 float4 + 2 float2 gathers, ~25 VALU.

__global__ __launch_bounds__(256) void attn_kernel(
    const float* __restrict__ efeat,
    const float* __restrict__ We, const float* __restrict__ be,
    const float* __restrict__ q, const float* __restrict__ qe,
    const float* __restrict__ k, const float* __restrict__ v,
    const float* __restrict__ xr, const float* __restrict__ x,
    const float* __restrict__ Wbeta,
    const float* __restrict__ ln1g, const float* __restrict__ ln1b,
    const int* __restrict__ offsets, const int2* __restrict__ sorted2,
    float* __restrict__ h, float* __restrict__ colsum)
{
    __shared__ float WeS[32][128];
    __shared__ float cs[4][128];
    const int tid = threadIdx.x;
    for (int i = tid; i < 4096; i += 256) ((float*)WeS)[i] = We[i];
    const int lane = tid & 63;
    const int wid = tid >> 6;
    const int f0 = 2 * lane;
    const int l8 = lane & 7;
    const int grp = lane & 56;

    const float be0 = be[f0], be1 = be[f0 + 1];
    const float wbo0 = Wbeta[f0],       wbo1 = Wbeta[f0 + 1];
    const float wbr0 = Wbeta[128 + f0], wbr1 = Wbeta[128 + f0 + 1];
    const float wbd0 = Wbeta[256 + f0], wbd1 = Wbeta[256 + f0 + 1];
    const float lg0 = ln1g[f0], lg1 = ln1g[f0 + 1];
    const float lb0 = ln1b[f0], lb1 = ln1b[f0 + 1];

    cs[wid][f0] = 0.f; cs[wid][f0 + 1] = 0.f;
    __syncthreads();

    const int gwave = blockIdx.x * 4 + wid;
    const int nwave = gridDim.x * 4;

    for (int node = gwave; node < NN; node += nwave) {
        const int beg = offsets[node];
        const int end = offsets[node + 1];
        const float2 qv = *(const float2*)(q + (size_t)node * 128 + f0);
        const float4 qev = *(const float4*)(qe + (size_t)node * 256 + 4 * lane);
        float qbe = qv.x * be0 + qv.y * be1;
        qbe += __shfl_xor(qbe, 1); qbe += __shfl_xor(qbe, 2); qbe += __shfl_xor(qbe, 4);
        const float qbe25 = qbe * 0.25f;

        float m = -1e30f, s = 0.f, a0 = 0.f, a1 = 0.f;
        float4 wef = f4z();

        int t = beg;
        for (; t + 4 <= end; t += 4) {
            int2 es[4];
            #pragma unroll
            for (int u = 0; u < 4; ++u) es[u] = sorted2[t + u];
            float4 efv[4]; float2 kv[4], vv[4];
            #pragma unroll
            for (int u = 0; u < 4; ++u) {
                efv[u] = *(const float4*)(efeat + (size_t)es[u].x * 32 + 4 * l8);
                kv[u]  = *(const float2*)(k + (size_t)es[u].y * 128 + f0);
                vv[u]  = *(const float2*)(v + (size_t)es[u].y * 128 + f0);
            }
            float lgt[4];
            #pragma unroll
            for (int u = 0; u < 4; ++u) {
                float part = qv.x * kv[u].x + qv.y * kv[u].y
                           + qev.x * efv[u].x + qev.y * efv[u].y
                           + qev.z * efv[u].z + qev.w * efv[u].w;
                part += __shfl_xor(part, 1);
                part += __shfl_xor(part, 2);
                part += __shfl_xor(part, 4);
                lgt[u] = part * 0.25f + qbe25;
            }
            #pragma unroll
            for (int u = 0; u < 4; ++u) {
                float nm = fmaxf(m, lgt[u]);
                float scale = __expf(m - nm);
                float p = __expf(lgt[u] - nm);
                m = nm;
                s = fmaf(s, scale, p);
                a0 = fmaf(a0, scale, p * vv[u].x);
                a1 = fmaf(a1, scale, p * vv[u].y);
                wef.x = fmaf(wef.x, scale, p * efv[u].x);
                wef.y = fmaf(wef.y, scale, p * efv[u].y);
                wef.z = fmaf(wef.z, scale, p * efv[u].z);
                wef.w = fmaf(wef.w, scale, p * efv[u].w);
            }
        }
        for (; t < end; ++t) {
            int2 es = sorted2[t];
            float4 efv = *(const float4*)(efeat + (size_t)es.x * 32 + 4 * l8);
            float2 kv  = *(const float2*)(k + (size_t)es.y * 128 + f0);
            float2 vv  = *(const float2*)(v + (size_t)es.y * 128 + f0);
            float part = qv.x * kv.x + qv.y * kv.y
                       + qev.x * efv.x + qev.y * efv.y + qev.z * efv.z + qev.w * efv.w;
            part += __shfl_xor(part, 1);
            part += __shfl_xor(part, 2);
            part += __shfl_xor(part, 4);
            float lgt = part * 0.25f + qbe25;
            float nm = fmaxf(m, lgt);
            float scale = __expf(m - nm);
            float p = __expf(lgt - nm);
            m = nm;
            s = fmaf(s, scale, p);
            a0 = fmaf(a0, scale, p * vv.x);
            a1 = fmaf(a1, scale, p * vv.y);
            wef.x = fmaf(wef.x, scale, p * efv.x);
            wef.y = fmaf(wef.y, scale, p * efv.y);
            wef.z = fmaf(wef.z, scale, p * efv.z);
            wef.w = fmaf(wef.w, scale, p * efv.w);
        }

        const float inv = 1.f / (s + 1e-16f);
        float o0 = fmaf(a0, inv, be0);
        float o1 = fmaf(a1, inv, be1);
        float wn0 = wef.x * inv, wn1 = wef.y * inv, wn2 = wef.z * inv, wn3 = wef.w * inv;
        // (Σ α ef) @ We restricted to this head's features
        float ew0 = 0.f, ew1 = 0.f;
        #pragma unroll
        for (int l2 = 0; l2 < 8; ++l2) {
            float b0 = __shfl(wn0, grp + l2);
            float b1 = __shfl(wn1, grp + l2);
            float b2 = __shfl(wn2, grp + l2);
            float b3 = __shfl(wn3, grp + l2);
            float2 w0 = *(const float2*)&WeS[4 * l2 + 0][f0];
            float2 w1 = *(const float2*)&WeS[4 * l2 + 1][f0];
            float2 w2 = *(const float2*)&WeS[4 * l2 + 2][f0];
            float2 w3 = *(const float2*)&WeS[4 * l2 + 3][f0];
            ew0 += b0 * w0.x + b1 * w1.x + b2 * w2.x + b3 * w3.x;
            ew1 += b0 * w0.y + b1 * w1.y + b2 * w2.y + b3 * w3.y;
        }
        o0 += ew0; o1 += ew1;

        const float2 xrv = *(const float2*)(xr + (size_t)node * 128 + f0);
        float bp = o0 * wbo0 + o1 * wbo1 + xrv.x * wbr0 + xrv.y * wbr1
                 + (o0 - xrv.x) * wbd0 + (o1 - xrv.y) * wbd1;
        #pragma unroll
        for (int msk = 1; msk < 64; msk <<= 1) bp += __shfl_xor(bp, msk);
        const float beta = 1.f / (1.f + __expf(-bp));
        const float2 xv = *(const float2*)(x + (size_t)node * 128 + f0);
        float t0 = beta * xrv.x + (1.f - beta) * o0 + xv.x;
        float t1 = beta * xrv.y + (1.f - beta) * o1 + xv.y;
        float sm = t0 + t1, sq = t0 * t0 + t1 * t1;
        #pragma unroll
        for (int msk = 1; msk < 64; msk <<= 1) { sm += __shfl_xor(sm, msk); sq += __shfl_xor(sq, msk); }
        const float mu = sm * (1.f / 128.f);
        const float var = sq * (1.f / 128.f) - mu * mu;
        const float rstd = rsqrtf(var + 1e-5f);
        const float h0 = fmaxf((t0 - mu) * rstd * lg0 + lb0, 0.f);
        const float h1 = fmaxf((t1 - mu) * rstd * lg1 + lb1, 0.f);
        *(float2*)(h + (size_t)node * 128 + f0) = make_float2(h0, h1);
        cs[wid][f0] += h0; cs[wid][f0 + 1] += h1;
    }
    __syncthreads();
    if (wid == 0) {
        float c0 = cs[0][f0] + cs[1][f0] + cs[2][f0] + cs[3][f0];
        float c1 = cs[0][f0 + 1] + cs[1][f0 + 1] + cs[2][f0 + 1] + cs[3][f0 + 1];
        atomicAdd(&colsum[f0], c0);
        atomicAdd(&colsum[f0 + 1], c1);
    }
}

// ---------------- global context (tiny) ----------------

__global__ __launch_bounds__(128) void gctx_kernel(
    const float* __restrict__ colsum,
    const float* __restrict__ Wr, const float* __restrict__ br,
    const float* __restrict__ Ww, const float* __restrict__ bw,
    const float* __restrict__ Wg, const float* __restrict__ bg,
    float* __restrict__ gc)
{
    __shared__ float hm[128], g[128], gb[128];
    const int f = threadIdx.x;
    hm[f] = colsum[f] * (1.f / (float)NN);
    __syncthreads();
    float a = br[f];
    for (int i = 0; i < 128; ++i) a += hm[i] * Wr[i * 128 + f];
    g[f] = fmaxf(a, 0.f);
    __syncthreads();
    float b = bw[f];
    for (int i = 0; i < 128; ++i) b += g[i] * Ww[i * 128 + f];
    gb[f] = b;
    gc[f] = b;
    __syncthreads();
    float c = bg[f];
    for (int i = 0; i < 128; ++i) c += gb[i] * Wg[(128 + i) * 128 + f];
    gc[128 + f] = c;
}

// ---------------- final: h@Wg[:128] + gate + LN2 fused ----------------

__global__ __launch_bounds__(256) void final_kernel(
    const float* __restrict__ h, const float* __restrict__ Wg,
    const float* __restrict__ gc,
    const float* __restrict__ ln2g, const float* __restrict__ ln2b,
    float* __restrict__ out)
{
    __shared__ float hs[32][128];
    __shared__ float ys[32][128];
    const int tid = threadIdx.x;
    const int row0 = blockIdx.x * 32;
    for (int i = tid; i < 1024; i += 256) {
        int r = i >> 5, c4 = i & 31;
        int gr = row0 + r;
        float4 val = f4z();
        if (gr < NN) val = ((const float4*)(h + (size_t)gr * 128))[c4];
        ((float4*)hs[r])[c4] = val;
    }
    __syncthreads();
    const int cg = tid & 31;
    const int rg = tid >> 5;
    float4 a[4];
    #pragma unroll
    for (int r = 0; r < 4; ++r) a[r] = f4z();
    #pragma unroll 2
    for (int kk = 0; kk < 128; ++kk) {
        float4 w4 = ((const float4*)(Wg + kk * 128))[cg];
        #pragma unroll
        for (int r = 0; r < 4; ++r) {
            float xv = hs[4 * rg + r][kk];
            a[r].x += xv * w4.x; a[r].y += xv * w4.y; a[r].z += xv * w4.z; a[r].w += xv * w4.w;
        }
    }
    const float4 gb = ((const float4*)gc)[cg];
    const float4 c2 = ((const float4*)(gc + 128))[cg];
    #pragma unroll
    for (int r = 0; r < 4; ++r) {
        int row = 4 * rg + r;
        float4 hv = ((float4*)hs[row])[cg];
        float4 y;
        float gx;
        gx = 1.f / (1.f + __expf(-(a[r].x + c2.x))); y.x = hv.x + gx * gb.x;
        gx = 1.f / (1.f + __expf(-(a[r].y + c2.y))); y.y = hv.y + gx * gb.y;
        gx = 1.f / (1.f + __expf(-(a[r].z + c2.z))); y.z = hv.z + gx * gb.z;
        gx = 1.f / (1.f + __expf(-(a[r].w + c2.w))); y.w = hv.w + gx * gb.w;
        ((float4*)ys[row])[cg] = y;
    }
    __syncthreads();
    const int lane = tid & 63;
    const int wid = tid >> 6;
    const int f0 = 2 * lane;
    const float lg0 = ln2g[f0], lg1 = ln2g[f0 + 1];
    const float lb0 = ln2b[f0], lb1 = ln2b[f0 + 1];
    for (int rr = 0; rr < 8; ++rr) {
        int row = wid * 8 + rr;
        int gr = row0 + row;
        if (gr >= NN) continue;
        float y0 = ys[row][f0], y1 = ys[row][f0 + 1];
        float sm = y0 + y1, sq = y0 * y0 + y1 * y1;
        #pragma unroll
        for (int msk = 1; msk < 64; msk <<= 1) { sm += __shfl_xor(sm, msk); sq += __shfl_xor(sq, msk); }
        float mu = sm * (1.f / 128.f);
        float var = sq * (1.f / 128.f) - mu * mu;
        float rstd = rsqrtf(var + 1e-5f);
        float o0 = (y0 - mu) * rstd * lg0 + lb0;
        float o1 = (y1 - mu) * rstd * lg1 + lb1;
        *(float2*)(out + (size_t)gr * 128 + f0) = make_float2(o0, o1);
    }
}

// ---------------- launch ----------------

extern "C" void kernel_launch(void* const* d_in, const int* in_sizes, int n_in,
                              void* d_out, int out_size, void* d_ws, size_t ws_size,
                              hipStream_t stream)
{
    const float* x    = (const float*)d_in[0];
    const int*   ei   = (const int*)d_in[1];
    const float* ef   = (const float*)d_in[2];
    const float* Wq   = (const float*)d_in[3];
    const float* bq   = (const float*)d_in[4];
    const float* Wk   = (const float*)d_in[5];
    const float* bk   = (const float*)d_in[6];
    const float* Wv   = (const float*)d_in[7];
    const float* bv   = (const float*)d_in[8];
    const float* We   = (const float*)d_in[9];
    const float* be   = (const float*)d_in[10];
    const float* Wsk  = (const float*)d_in[11];
    const float* bsk  = (const float*)d_in[12];
    const float* Wbeta= (const float*)d_in[13];
    const float* g1   = (const float*)d_in[14];
    const float* b1   = (const float*)d_in[15];
    const float* Wr   = (const float*)d_in[16];
    const float* br   = (const float*)d_in[17];
    const float* Ww   = (const float*)d_in[18];
    const float* bw   = (const float*)d_in[19];
    const float* Wg   = (const float*)d_in[20];
    const float* bg   = (const float*)d_in[21];
    const float* g2   = (const float*)d_in[22];
    const float* b2   = (const float*)d_in[23];
    float* out = (float*)d_out;

    const size_t NF = (size_t)NN * 128;
    float* q      = (float*)d_ws;
    float* k      = q + NF;
    float* v      = k + NF;
    float* xr     = v + NF;
    float* h      = xr + NF;
    float* qe     = h + NF;                  // N*256
    float* colsum = qe + (size_t)NN * 256;
    float* gc     = colsum + 128;            // 256 floats
    float* Wqe    = gc + 256;                // 128*256
    int* counts   = (int*)(Wqe + 128 * 256);
    int* offsets  = counts + NN;             // NN+2 (pad for alignment)
    int* cursor   = offsets + NN + 2;
    int2* sorted2 = (int2*)(cursor + NN);    // EE int2

    hipMemsetAsync(counts, 0, NN * sizeof(int), stream);
    hipMemsetAsync(colsum, 0, 128 * sizeof(float), stream);

    hist_kernel<<<2048, 256, 0, stream>>>(ei, counts);
    scan_kernel<<<1, 1024, 0, stream>>>(counts, offsets, cursor);
    scatter_kernel<<<2048, 256, 0, stream>>>(ei, cursor, sorted2);
    build_wqe<<<128, 256, 0, stream>>>(We, Wqe);
    proj_kernel<<<(NN + 31) / 32, 256, 0, stream>>>(x, Wq, bq, Wk, bk, Wv, bv, Wsk, bsk, q, k, v, xr);
    qe_kernel<<<(NN + 15) / 16, 256, 0, stream>>>(q, Wqe, qe);
    attn_kernel<<<2048, 256, 0, stream>>>(ef, We, be, q, qe, k, v, xr, x, Wbeta, g1, b1,
                                          offsets, sorted2, h, colsum);
    gctx_kernel<<<1, 128, 0, stream>>>(colsum, Wr, br, Ww, bw, Wg, bg, gc);
    final_kernel<<<(NN + 31) / 32, 256, 0, stream>>>(h, Wg, gc, g2, b2, out);
}

// Round 3
// 970.126 us; speedup vs baseline: 1.5172x; 1.0434x over previous
//
#include <hip/hip_runtime.h>

#define NN 50000
#define EE 1600000

static __device__ __forceinline__ float4 f4z() { return make_float4(0.f, 0.f, 0.f, 0.f); }

// ---------------- CSR build ----------------

__global__ __launch_bounds__(256) void hist_kernel(const int* __restrict__ ei, int* __restrict__ counts)
{
    int i = blockIdx.x * blockDim.x + threadIdx.x;
    int stride = gridDim.x * blockDim.x;
    for (; i < EE; i += stride) atomicAdd(&counts[ei[EE + i]], 1);
}

__global__ __launch_bounds__(1024) void scan_kernel(const int* __restrict__ counts,
                                                    int* __restrict__ offsets,
                                                    int* __restrict__ cursor)
{
    __shared__ int buf[1024];
    const int t = threadIdx.x;
    const int M = 49;
    const int base = t * M;
    int s = 0;
    for (int j = 0; j < M; ++j) { int i = base + j; if (i < NN) s += counts[i]; }
    buf[t] = s;
    __syncthreads();
    for (int ofs = 1; ofs < 1024; ofs <<= 1) {
        int add = (t >= ofs) ? buf[t - ofs] : 0;
        __syncthreads();
        buf[t] += add;
        __syncthreads();
    }
    int run = buf[t] - s;
    for (int j = 0; j < M; ++j) {
        int i = base + j;
        if (i < NN) { offsets[i] = run; cursor[i] = run; run += counts[i]; }
        else if (i == NN) { offsets[NN] = run; }
    }
}

__global__ __launch_bounds__(256) void scatter_kernel(const int* __restrict__ ei,
                                                      int* __restrict__ cursor,
                                                      int2* __restrict__ sorted2)
{
    int i = blockIdx.x * blockDim.x + threadIdx.x;
    int stride = gridDim.x * blockDim.x;
    for (; i < EE; i += stride) {
        int srcn = ei[i];
        int d = ei[EE + i];
        int pos = atomicAdd(&cursor[d], 1);
        sorted2[pos] = make_int2(i, srcn);
    }
}

// ---------------- fused q/k/v/xr projection ----------------

__global__ __launch_bounds__(256) void proj_kernel(
    const float* __restrict__ x,
    const float* __restrict__ Wq, const float* __restrict__ bq,
    const float* __restrict__ Wk, const float* __restrict__ bk,
    const float* __restrict__ Wv, const float* __restrict__ bv,
    const float* __restrict__ Ws, const float* __restrict__ bs,
    float* __restrict__ q, float* __restrict__ k,
    float* __restrict__ v, float* __restrict__ xr)
{
    __shared__ float xs[32][128];
    const int tid = threadIdx.x;
    const int row0 = blockIdx.x * 32;
    for (int i = tid; i < 1024; i += 256) {
        int r = i >> 5, c4 = i & 31;
        int gr = row0 + r;
        float4 val = f4z();
        if (gr < NN) val = ((const float4*)(x + (size_t)gr * 128))[c4];
        ((float4*)xs[r])[c4] = val;
    }
    __syncthreads();
    const int cg = tid & 31;
    const int rg = tid >> 5;
    float4 aq[4], ak[4], av[4], as_[4];
    #pragma unroll
    for (int r = 0; r < 4; ++r) { aq[r] = f4z(); ak[r] = f4z(); av[r] = f4z(); as_[r] = f4z(); }
    #pragma unroll 2
    for (int kk = 0; kk < 128; ++kk) {
        float4 wq = ((const float4*)(Wq + kk * 128))[cg];
        float4 wk = ((const float4*)(Wk + kk * 128))[cg];
        float4 wv = ((const float4*)(Wv + kk * 128))[cg];
        float4 ws = ((const float4*)(Ws + kk * 128))[cg];
        #pragma unroll
        for (int r = 0; r < 4; ++r) {
            float xv = xs[4 * rg + r][kk];
            aq[r].x += xv * wq.x; aq[r].y += xv * wq.y; aq[r].z += xv * wq.z; aq[r].w += xv * wq.w;
            ak[r].x += xv * wk.x; ak[r].y += xv * wk.y; ak[r].z += xv * wk.z; ak[r].w += xv * wk.w;
            av[r].x += xv * wv.x; av[r].y += xv * wv.y; av[r].z += xv * wv.z; av[r].w += xv * wv.w;
            as_[r].x += xv * ws.x; as_[r].y += xv * ws.y; as_[r].z += xv * ws.z; as_[r].w += xv * ws.w;
        }
    }
    const float4 bq4 = ((const float4*)bq)[cg];
    const float4 bk4 = ((const float4*)bk)[cg];
    const float4 bv4 = ((const float4*)bv)[cg];
    const float4 bs4 = ((const float4*)bs)[cg];
    #pragma unroll
    for (int r = 0; r < 4; ++r) {
        int gr = row0 + 4 * rg + r;
        if (gr >= NN) continue;
        float4 o;
        o.x = aq[r].x + bq4.x; o.y = aq[r].y + bq4.y; o.z = aq[r].z + bq4.z; o.w = aq[r].w + bq4.w;
        ((float4*)(q + (size_t)gr * 128))[cg] = o;
        o.x = ak[r].x + bk4.x; o.y = ak[r].y + bk4.y; o.z = ak[r].z + bk4.z; o.w = ak[r].w + bk4.w;
        ((float4*)(k + (size_t)gr * 128))[cg] = o;
        o.x = av[r].x + bv4.x; o.y = av[r].y + bv4.y; o.z = av[r].z + bv4.z; o.w = av[r].w + bv4.w;
        ((float4*)(v + (size_t)gr * 128))[cg] = o;
        o.x = as_[r].x + bs4.x; o.y = as_[r].y + bs4.y; o.z = as_[r].z + bs4.z; o.w = as_[r].w + bs4.w;
        ((float4*)(xr + (size_t)gr * 128))[cg] = o;
    }
}

// ---------------- qe[n, h*32+d] = sum over head-h's 16 feats of q*We (sparse) ----------------

__global__ __launch_bounds__(256) void qe_small(const float* __restrict__ q,
                                                const float* __restrict__ We,
                                                float* __restrict__ qe)
{
    int idx = blockIdx.x * 256 + threadIdx.x;
    if (idx >= NN * 64) return;
    int n = idx >> 6, r = idx & 63;
    int h = r >> 3, d0 = (r & 7) << 2;
    const float* qrow = q + (size_t)n * 128 + h * 16;
    float acc0 = 0.f, acc1 = 0.f, acc2 = 0.f, acc3 = 0.f;
    #pragma unroll
    for (int c = 0; c < 4; ++c) {
        float4 qf = *(const float4*)(qrow + 4 * c);
        float4 w0 = *(const float4*)(We + (d0 + 0) * 128 + h * 16 + 4 * c);
        float4 w1 = *(const float4*)(We + (d0 + 1) * 128 + h * 16 + 4 * c);
        float4 w2 = *(const float4*)(We + (d0 + 2) * 128 + h * 16 + 4 * c);
        float4 w3 = *(const float4*)(We + (d0 + 3) * 128 + h * 16 + 4 * c);
        acc0 += qf.x * w0.x + qf.y * w0.y + qf.z * w0.z + qf.w * w0.w;
        acc1 += qf.x * w1.x + qf.y * w1.y + qf.z * w1.z + qf.w * w1.w;
        acc2 += qf.x * w2.x + qf.y * w2.y + qf.z * w2.z + qf.w * w2.w;
        acc3 += qf.x * w3.x + qf.y * w3.y + qf.z * w3.z + qf.w * w3.w;
    }
    *(float4*)(qe + (size_t)n * 256 + h * 32 + d0) = make_float4(acc0, acc1, acc2, acc3);
}

// ---------------- fused attention + beta-skip + LN1 + relu ----------------
// one wave per dst node; 8-edge batches, next-batch index prefetch, tree-combined softmax.

__global__ __launch_bounds__(256) void attn_kernel(
    const float* __restrict__ efeat,
    const float* __restrict__ We, const float* __restrict__ be,
    const float* __restrict__ q, const float* __restrict__ qe,
    const float* __restrict__ k, const float* __restrict__ v,
    const float* __restrict__ xr, const float* __restrict__ x,
    const float* __restrict__ Wbeta,
    const float* __restrict__ ln1g, const float* __restrict__ ln1b,
    const int* __restrict__ offsets, const int2* __restrict__ sorted2,
    float* __restrict__ h, float* __restrict__ colsum)
{
    __shared__ float WeS[32][128];
    __shared__ float cs[4][128];
    const int tid = threadIdx.x;
    for (int i = tid; i < 4096; i += 256) ((float*)WeS)[i] = We[i];
    const int lane = tid & 63;
    const int wid = tid >> 6;
    const int f0 = 2 * lane;
    const int l8 = lane & 7;
    const int grp = lane & 56;

    const float be0 = be[f0], be1 = be[f0 + 1];
    const float wbo0 = Wbeta[f0],       wbo1 = Wbeta[f0 + 1];
    const float wbr0 = Wbeta[128 + f0], wbr1 = Wbeta[128 + f0 + 1];
    const float wbd0 = Wbeta[256 + f0], wbd1 = Wbeta[256 + f0 + 1];
    const float lg0 = ln1g[f0], lg1 = ln1g[f0 + 1];
    const float lb0 = ln1b[f0], lb1 = ln1b[f0 + 1];

    cs[wid][f0] = 0.f; cs[wid][f0 + 1] = 0.f;
    __syncthreads();

    const int gwave = blockIdx.x * 4 + wid;
    const int nwave = gridDim.x * 4;

    for (int node = gwave; node < NN; node += nwave) {
        const int beg = offsets[node];
        const int end = offsets[node + 1];
        const float2 qv = *(const float2*)(q + (size_t)node * 128 + f0);
        const float4 qev = *(const float4*)(qe + (size_t)node * 256 + 4 * lane);
        float qbe = qv.x * be0 + qv.y * be1;
        qbe += __shfl_xor(qbe, 1); qbe += __shfl_xor(qbe, 2); qbe += __shfl_xor(qbe, 4);
        const float qbe25 = qbe * 0.25f;

        float m = -1e30f, s = 0.f, a0 = 0.f, a1 = 0.f;
        float4 wef = f4z();

        if (beg < end) {
            int2 es[8], esn[8];
            {
                int cn = end - beg;
                #pragma unroll
                for (int u = 0; u < 8; ++u) es[u] = sorted2[beg + (u < cn ? u : cn - 1)];
            }
            for (int t = beg; t < end; t += 8) {
                const int cnt = end - t;          // >= 1; may exceed 8
                // ---- issue 24 gathers for the current batch ----
                float4 efv[8]; float2 kv[8], vv[8];
                #pragma unroll
                for (int u = 0; u < 8; ++u) {
                    efv[u] = *(const float4*)(efeat + (size_t)es[u].x * 32 + 4 * l8);
                    kv[u]  = *(const float2*)(k + (size_t)es[u].y * 128 + f0);
                    vv[u]  = *(const float2*)(v + (size_t)es[u].y * 128 + f0);
                }
                // ---- prefetch next batch's indices under the gather latency ----
                const int tn = t + 8;
                if (tn < end) {
                    int cn = end - tn;
                    #pragma unroll
                    for (int u = 0; u < 8; ++u) esn[u] = sorted2[tn + (u < cn ? u : cn - 1)];
                }
                // ---- logits (parallel across 8 edges) ----
                float lgt[8];
                #pragma unroll
                for (int u = 0; u < 8; ++u) {
                    float part = qv.x * kv[u].x + qv.y * kv[u].y
                               + qev.x * efv[u].x + qev.y * efv[u].y
                               + qev.z * efv[u].z + qev.w * efv[u].w;
                    part += __shfl_xor(part, 1);
                    part += __shfl_xor(part, 2);
                    part += __shfl_xor(part, 4);
                    lgt[u] = (u < cnt) ? (part * 0.25f + qbe25) : -1e30f;
                }
                // ---- batch tree combine ----
                float m01 = fmaxf(lgt[0], lgt[1]), m23 = fmaxf(lgt[2], lgt[3]);
                float m45 = fmaxf(lgt[4], lgt[5]), m67 = fmaxf(lgt[6], lgt[7]);
                float bm = fmaxf(fmaxf(m01, m23), fmaxf(m45, m67));
                float p[8];
                #pragma unroll
                for (int u = 0; u < 8; ++u) p[u] = __expf(lgt[u] - bm);
                float bsA = 0.f, bsB = 0.f, b0A = 0.f, b0B = 0.f, b1A = 0.f, b1B = 0.f;
                float4 befA = f4z(), befB = f4z();
                #pragma unroll
                for (int u = 0; u < 8; u += 2) {
                    bsA += p[u];     bsB += p[u + 1];
                    b0A = fmaf(p[u], vv[u].x, b0A);       b0B = fmaf(p[u + 1], vv[u + 1].x, b0B);
                    b1A = fmaf(p[u], vv[u].y, b1A);       b1B = fmaf(p[u + 1], vv[u + 1].y, b1B);
                    befA.x = fmaf(p[u], efv[u].x, befA.x); befB.x = fmaf(p[u + 1], efv[u + 1].x, befB.x);
                    befA.y = fmaf(p[u], efv[u].y, befA.y); befB.y = fmaf(p[u + 1], efv[u + 1].y, befB.y);
                    befA.z = fmaf(p[u], efv[u].z, befA.z); befB.z = fmaf(p[u + 1], efv[u + 1].z, befB.z);
                    befA.w = fmaf(p[u], efv[u].w, befA.w); befB.w = fmaf(p[u + 1], efv[u + 1].w, befB.w);
                }
                // ---- single merge into running state ----
                const float nm = fmaxf(m, bm);
                const float so = __expf(m - nm);
                const float sn = __expf(bm - nm);
                s  = s  * so + (bsA + bsB) * sn;
                a0 = a0 * so + (b0A + b0B) * sn;
                a1 = a1 * so + (b1A + b1B) * sn;
                wef.x = wef.x * so + (befA.x + befB.x) * sn;
                wef.y = wef.y * so + (befA.y + befB.y) * sn;
                wef.z = wef.z * so + (befA.z + befB.z) * sn;
                wef.w = wef.w * so + (befA.w + befB.w) * sn;
                m = nm;
                #pragma unroll
                for (int u = 0; u < 8; ++u) es[u] = esn[u];
            }
        }

        const float inv = 1.f / (s + 1e-16f);
        float o0 = fmaf(a0, inv, be0);
        float o1 = fmaf(a1, inv, be1);
        float wn0 = wef.x * inv, wn1 = wef.y * inv, wn2 = wef.z * inv, wn3 = wef.w * inv;
        float ew0 = 0.f, ew1 = 0.f;
        #pragma unroll
        for (int l2 = 0; l2 < 8; ++l2) {
            float b0 = __shfl(wn0, grp + l2);
            float b1 = __shfl(wn1, grp + l2);
            float b2 = __shfl(wn2, grp + l2);
            float b3 = __shfl(wn3, grp + l2);
            float2 w0 = *(const float2*)&WeS[4 * l2 + 0][f0];
            float2 w1 = *(const float2*)&WeS[4 * l2 + 1][f0];
            float2 w2 = *(const float2*)&WeS[4 * l2 + 2][f0];
            float2 w3 = *(const float2*)&WeS[4 * l2 + 3][f0];
            ew0 += b0 * w0.x + b1 * w1.x + b2 * w2.x + b3 * w3.x;
            ew1 += b0 * w0.y + b1 * w1.y + b2 * w2.y + b3 * w3.y;
        }
        o0 += ew0; o1 += ew1;
        if (end == beg) { o0 = 0.f; o1 = 0.f; }   // no incoming edges -> out row is 0

        const float2 xrv = *(const float2*)(xr + (size_t)node * 128 + f0);
        float bp = o0 * wbo0 + o1 * wbo1 + xrv.x * wbr0 + xrv.y * wbr1
                 + (o0 - xrv.x) * wbd0 + (o1 - xrv.y) * wbd1;
        #pragma unroll
        for (int msk = 1; msk < 64; msk <<= 1) bp += __shfl_xor(bp, msk);
        const float beta = 1.f / (1.f + __expf(-bp));
        const float2 xv = *(const float2*)(x + (size_t)node * 128 + f0);
        float t0 = beta * xrv.x + (1.f - beta) * o0 + xv.x;
        float t1 = beta * xrv.y + (1.f - beta) * o1 + xv.y;
        float sm = t0 + t1, sq = t0 * t0 + t1 * t1;
        #pragma unroll
        for (int msk = 1; msk < 64; msk <<= 1) { sm += __shfl_xor(sm, msk); sq += __shfl_xor(sq, msk); }
        const float mu = sm * (1.f / 128.f);
        const float var = sq * (1.f / 128.f) - mu * mu;
        const float rstd = rsqrtf(var + 1e-5f);
        const float h0 = fmaxf((t0 - mu) * rstd * lg0 + lb0, 0.f);
        const float h1 = fmaxf((t1 - mu) * rstd * lg1 + lb1, 0.f);
        *(float2*)(h + (size_t)node * 128 + f0) = make_float2(h0, h1);
        cs[wid][f0] += h0; cs[wid][f0 + 1] += h1;
    }
    __syncthreads();
    if (wid == 0) {
        float c0 = cs[0][f0] + cs[1][f0] + cs[2][f0] + cs[3][f0];
        float c1 = cs[0][f0 + 1] + cs[1][f0 + 1] + cs[2][f0 + 1] + cs[3][f0 + 1];
        atomicAdd(&colsum[f0], c0);
        atomicAdd(&colsum[f0 + 1], c1);
    }
}

// ---------------- global context (tiny) ----------------

__global__ __launch_bounds__(128) void gctx_kernel(
    const float* __restrict__ colsum,
    const float* __restrict__ Wr, const float* __restrict__ br,
    const float* __restrict__ Ww, const float* __restrict__ bw,
    const float* __restrict__ Wg, const float* __restrict__ bg,
    float* __restrict__ gc)
{
    __shared__ float hm[128], g[128], gb[128];
    const int f = threadIdx.x;
    hm[f] = colsum[f] * (1.f / (float)NN);
    __syncthreads();
    float a = br[f];
    for (int i = 0; i < 128; ++i) a += hm[i] * Wr[i * 128 + f];
    g[f] = fmaxf(a, 0.f);
    __syncthreads();
    float b = bw[f];
    for (int i = 0; i < 128; ++i) b += g[i] * Ww[i * 128 + f];
    gb[f] = b;
    gc[f] = b;
    __syncthreads();
    float c = bg[f];
    for (int i = 0; i < 128; ++i) c += gb[i] * Wg[(128 + i) * 128 + f];
    gc[128 + f] = c;
}

// ---------------- final: h@Wg[:128] + gate + LN2 fused ----------------

__global__ __launch_bounds__(256) void final_kernel(
    const float* __restrict__ h, const float* __restrict__ Wg,
    const float* __restrict__ gc,
    const float* __restrict__ ln2g, const float* __restrict__ ln2b,
    float* __restrict__ out)
{
    __shared__ float hs[32][128];
    __shared__ float ys[32][128];
    const int tid = threadIdx.x;
    const int row0 = blockIdx.x * 32;
    for (int i = tid; i < 1024; i += 256) {
        int r = i >> 5, c4 = i & 31;
        int gr = row0 + r;
        float4 val = f4z();
        if (gr < NN) val = ((const float4*)(h + (size_t)gr * 128))[c4];
        ((float4*)hs[r])[c4] = val;
    }
    __syncthreads();
    const int cg = tid & 31;
    const int rg = tid >> 5;
    float4 a[4];
    #pragma unroll
    for (int r = 0; r < 4; ++r) a[r] = f4z();
    #pragma unroll 2
    for (int kk = 0; kk < 128; ++kk) {
        float4 w4 = ((const float4*)(Wg + kk * 128))[cg];
        #pragma unroll
        for (int r = 0; r < 4; ++r) {
            float xv = hs[4 * rg + r][kk];
            a[r].x += xv * w4.x; a[r].y += xv * w4.y; a[r].z += xv * w4.z; a[r].w += xv * w4.w;
        }
    }
    const float4 gb = ((const float4*)gc)[cg];
    const float4 c2 = ((const float4*)(gc + 128))[cg];
    #pragma unroll
    for (int r = 0; r < 4; ++r) {
        int row = 4 * rg + r;
        float4 hv = ((float4*)hs[row])[cg];
        float4 y;
        float gx;
        gx = 1.f / (1.f + __expf(-(a[r].x + c2.x))); y.x = hv.x + gx * gb.x;
        gx = 1.f / (1.f + __expf(-(a[r].y + c2.y))); y.y = hv.y + gx * gb.y;
        gx = 1.f / (1.f + __expf(-(a[r].z + c2.z))); y.z = hv.z + gx * gb.z;
        gx = 1.f / (1.f + __expf(-(a[r].w + c2.w))); y.w = hv.w + gx * gb.w;
        ((float4*)ys[row])[cg] = y;
    }
    __syncthreads();
    const int lane = tid & 63;
    const int wid = tid >> 6;
    const int f0 = 2 * lane;
    const float lg0 = ln2g[f0], lg1 = ln2g[f0 + 1];
    const float lb0 = ln2b[f0], lb1 = ln2b[f0 + 1];
    for (int rr = 0; rr < 8; ++rr) {
        int row = wid * 8 + rr;
        int gr = row0 + row;
        if (gr >= NN) continue;
        float y0 = ys[row][f0], y1 = ys[row][f0 + 1];
        float sm = y0 + y1, sq = y0 * y0 + y1 * y1;
        #pragma unroll
        for (int msk = 1; msk < 64; msk <<= 1) { sm += __shfl_xor(sm, msk); sq += __shfl_xor(sq, msk); }
        float mu = sm * (1.f / 128.f);
        float var = sq * (1.f / 128.f) - mu * mu;
        float rstd = rsqrtf(var + 1e-5f);
        float o0 = (y0 - mu) * rstd * lg0 + lb0;
        float o1 = (y1 - mu) * rstd * lg1 + lb1;
        *(float2*)(out + (size_t)gr * 128 + f0) = make_float2(o0, o1);
    }
}

// ---------------- launch ----------------

extern "C" void kernel_launch(void* const* d_in, const int* in_sizes, int n_in,
                              void* d_out, int out_size, void* d_ws, size_t ws_size,
                              hipStream_t stream)
{
    const float* x    = (const float*)d_in[0];
    const int*   ei   = (const int*)d_in[1];
    const float* ef   = (const float*)d_in[2];
    const float* Wq   = (const float*)d_in[3];
    const float* bq   = (const float*)d_in[4];
    const float* Wk   = (const float*)d_in[5];
    const float* bk   = (const float*)d_in[6];
    const float* Wv   = (const float*)d_in[7];
    const float* bv   = (const float*)d_in[8];
    const float* We   = (const float*)d_in[9];
    const float* be   = (const float*)d_in[10];
    const float* Wsk  = (const float*)d_in[11];
    const float* bsk  = (const float*)d_in[12];
    const float* Wbeta= (const float*)d_in[13];
    const float* g1   = (const float*)d_in[14];
    const float* b1   = (const float*)d_in[15];
    const float* Wr   = (const float*)d_in[16];
    const float* br   = (const float*)d_in[17];
    const float* Ww   = (const float*)d_in[18];
    const float* bw   = (const float*)d_in[19];
    const float* Wg   = (const float*)d_in[20];
    const float* bg   = (const float*)d_in[21];
    const float* g2   = (const float*)d_in[22];
    const float* b2   = (const float*)d_in[23];
    float* out = (float*)d_out;

    const size_t NF = (size_t)NN * 128;
    float* q      = (float*)d_ws;
    float* k      = q + NF;
    float* v      = k + NF;
    float* xr     = v + NF;
    float* h      = xr + NF;
    float* qe     = h + NF;                  // N*256
    float* colsum = qe + (size_t)NN * 256;
    float* gc     = colsum + 128;            // 256 floats
    int* counts   = (int*)(gc + 256);
    int* offsets  = counts + NN;             // NN+2 (pad for alignment)
    int* cursor   = offsets + NN + 2;
    int2* sorted2 = (int2*)(cursor + NN);    // EE int2

    hipMemsetAsync(counts, 0, NN * sizeof(int), stream);
    hipMemsetAsync(colsum, 0, 128 * sizeof(float), stream);

    hist_kernel<<<2048, 256, 0, stream>>>(ei, counts);
    scan_kernel<<<1, 1024, 0, stream>>>(counts, offsets, cursor);
    scatter_kernel<<<2048, 256, 0, stream>>>(ei, cursor, sorted2);
    proj_kernel<<<(NN + 31) / 32, 256, 0, stream>>>(x, Wq, bq, Wk, bk, Wv, bv, Wsk, bsk, q, k, v, xr);
    qe_small<<<(NN * 64 + 255) / 256, 256, 0, stream>>>(q, We, qe);
    attn_kernel<<<2048, 256, 0, stream>>>(ef, We, be, q, qe, k, v, xr, x, Wbeta, g1, b1,
                                          offsets, sorted2, h, colsum);
    gctx_kernel<<<1, 128, 0, stream>>>(colsum, Wr, br, Ww, bw, Wg, bg, gc);
    final_kernel<<<(NN + 31) / 32, 256, 0, stream>>>(h, Wg, gc, g2, b2, out);
}

// Round 4
// 860.740 us; speedup vs baseline: 1.7100x; 1.1271x over previous
//
#include <hip/hip_runtime.h>
#include <hip/hip_fp16.h>

#define NN 50000
#define EE 1600000

static __device__ __forceinline__ float4 f4z() { return make_float4(0.f, 0.f, 0.f, 0.f); }

// ---------------- CSR build ----------------

__global__ __launch_bounds__(256) void hist_kernel(const int* __restrict__ ei, int* __restrict__ counts)
{
    int i = blockIdx.x * blockDim.x + threadIdx.x;
    int stride = gridDim.x * blockDim.x;
    for (; i < EE; i += stride) atomicAdd(&counts[ei[EE + i]], 1);
}

__global__ __launch_bounds__(1024) void scan_kernel(const int* __restrict__ counts,
                                                    int* __restrict__ offsets,
                                                    int* __restrict__ cursor)
{
    __shared__ int wsum[16];
    __shared__ int wpre[16];
    __shared__ int carrys;
    const int t = threadIdx.x;
    const int lane = t & 63, wid = t >> 6;
    if (t == 0) carrys = 0;
    __syncthreads();
    for (int base = 0; base <= NN; base += 1024) {
        int i = base + t;
        int orig = (i < NN) ? counts[i] : 0;
        int val = orig;
        #pragma unroll
        for (int ofs = 1; ofs < 64; ofs <<= 1) {
            int n = __shfl_up(val, ofs);
            if (lane >= ofs) val += n;
        }
        if (lane == 63) wsum[wid] = val;
        __syncthreads();
        if (t < 16) {
            int w = wsum[t];
            #pragma unroll
            for (int ofs = 1; ofs < 16; ofs <<= 1) {
                int n = __shfl_up(w, ofs);
                if (t >= ofs) w += n;
            }
            wpre[t] = w;
        }
        __syncthreads();
        int carry = carrys;
        int incl = val + (wid ? wpre[wid - 1] : 0);
        int excl = incl - orig + carry;
        if (i < NN) { offsets[i] = excl; cursor[i] = excl; }
        else if (i == NN) offsets[NN] = excl;
        __syncthreads();
        if (t == 1023) carrys = carry + incl;
        __syncthreads();
    }
}

__global__ __launch_bounds__(256) void scatter_kernel(const int* __restrict__ ei,
                                                      int* __restrict__ cursor,
                                                      int2* __restrict__ sorted2)
{
    int i = blockIdx.x * blockDim.x + threadIdx.x;
    int stride = gridDim.x * blockDim.x;
    for (; i < EE; i += stride) {
        int srcn = ei[i];
        int d = ei[EE + i];
        int pos = atomicAdd(&cursor[d], 1);
        sorted2[pos] = make_int2(i, srcn);
    }
}

// ---------------- fused q/kv(fp16)/xr projection ----------------

__global__ __launch_bounds__(256) void proj_kernel(
    const float* __restrict__ x,
    const float* __restrict__ Wq, const float* __restrict__ bq,
    const float* __restrict__ Wk, const float* __restrict__ bk,
    const float* __restrict__ Wv, const float* __restrict__ bv,
    const float* __restrict__ Ws, const float* __restrict__ bs,
    float* __restrict__ q, __half2* __restrict__ kvh,
    float* __restrict__ xr)
{
    __shared__ float xs[32][128];
    const int tid = threadIdx.x;
    const int row0 = blockIdx.x * 32;
    for (int i = tid; i < 1024; i += 256) {
        int r = i >> 5, c4 = i & 31;
        int gr = row0 + r;
        float4 val = f4z();
        if (gr < NN) val = ((const float4*)(x + (size_t)gr * 128))[c4];
        ((float4*)xs[r])[c4] = val;
    }
    __syncthreads();
    const int cg = tid & 31;
    const int rg = tid >> 5;
    float4 aq[4], ak[4], av[4], as_[4];
    #pragma unroll
    for (int r = 0; r < 4; ++r) { aq[r] = f4z(); ak[r] = f4z(); av[r] = f4z(); as_[r] = f4z(); }
    #pragma unroll 2
    for (int kk = 0; kk < 128; ++kk) {
        float4 wq = ((const float4*)(Wq + kk * 128))[cg];
        float4 wk = ((const float4*)(Wk + kk * 128))[cg];
        float4 wv = ((const float4*)(Wv + kk * 128))[cg];
        float4 ws = ((const float4*)(Ws + kk * 128))[cg];
        #pragma unroll
        for (int r = 0; r < 4; ++r) {
            float xv = xs[4 * rg + r][kk];
            aq[r].x += xv * wq.x; aq[r].y += xv * wq.y; aq[r].z += xv * wq.z; aq[r].w += xv * wq.w;
            ak[r].x += xv * wk.x; ak[r].y += xv * wk.y; ak[r].z += xv * wk.z; ak[r].w += xv * wk.w;
            av[r].x += xv * wv.x; av[r].y += xv * wv.y; av[r].z += xv * wv.z; av[r].w += xv * wv.w;
            as_[r].x += xv * ws.x; as_[r].y += xv * ws.y; as_[r].z += xv * ws.z; as_[r].w += xv * ws.w;
        }
    }
    const float4 bq4 = ((const float4*)bq)[cg];
    const float4 bk4 = ((const float4*)bk)[cg];
    const float4 bv4 = ((const float4*)bv)[cg];
    const float4 bs4 = ((const float4*)bs)[cg];
    #pragma unroll
    for (int r = 0; r < 4; ++r) {
        int gr = row0 + 4 * rg + r;
        if (gr >= NN) continue;
        float4 o;
        o.x = aq[r].x + bq4.x; o.y = aq[r].y + bq4.y; o.z = aq[r].z + bq4.z; o.w = aq[r].w + bq4.w;
        ((float4*)(q + (size_t)gr * 128))[cg] = o;
        float kx = ak[r].x + bk4.x, ky = ak[r].y + bk4.y, kz = ak[r].z + bk4.z, kw = ak[r].w + bk4.w;
        float vx = av[r].x + bv4.x, vy = av[r].y + bv4.y, vz = av[r].z + bv4.z, vw = av[r].w + bv4.w;
        union { __half2 h2[4]; float4 f4; } up;
        up.h2[0] = __floats2half2_rn(kx, vx);
        up.h2[1] = __floats2half2_rn(ky, vy);
        up.h2[2] = __floats2half2_rn(kz, vz);
        up.h2[3] = __floats2half2_rn(kw, vw);
        *((float4*)(kvh + (size_t)gr * 128 + 4 * cg)) = up.f4;
        o.x = as_[r].x + bs4.x; o.y = as_[r].y + bs4.y; o.z = as_[r].z + bs4.z; o.w = as_[r].w + bs4.w;
        ((float4*)(xr + (size_t)gr * 128))[cg] = o;
    }
}

// ---------------- qe[n, h*32+d] (fp16 out) ----------------

__global__ __launch_bounds__(256) void qe_small(const float* __restrict__ q,
                                                const float* __restrict__ We,
                                                __half* __restrict__ qeh)
{
    int idx = blockIdx.x * 256 + threadIdx.x;
    if (idx >= NN * 64) return;
    int n = idx >> 6, r = idx & 63;
    int h = r >> 3, d0 = (r & 7) << 2;
    const float* qrow = q + (size_t)n * 128 + h * 16;
    float acc0 = 0.f, acc1 = 0.f, acc2 = 0.f, acc3 = 0.f;
    #pragma unroll
    for (int c = 0; c < 4; ++c) {
        float4 qf = *(const float4*)(qrow + 4 * c);
        float4 w0 = *(const float4*)(We + (d0 + 0) * 128 + h * 16 + 4 * c);
        float4 w1 = *(const float4*)(We + (d0 + 1) * 128 + h * 16 + 4 * c);
        float4 w2 = *(const float4*)(We + (d0 + 2) * 128 + h * 16 + 4 * c);
        float4 w3 = *(const float4*)(We + (d0 + 3) * 128 + h * 16 + 4 * c);
        acc0 += qf.x * w0.x + qf.y * w0.y + qf.z * w0.z + qf.w * w0.w;
        acc1 += qf.x * w1.x + qf.y * w1.y + qf.z * w1.z + qf.w * w1.w;
        acc2 += qf.x * w2.x + qf.y * w2.y + qf.z * w2.z + qf.w * w2.w;
        acc3 += qf.x * w3.x + qf.y * w3.y + qf.z * w3.z + qf.w * w3.w;
    }
    union { __half2 h2[2]; float2 f2; } u;
    u.h2[0] = __floats2half2_rn(acc0, acc1);
    u.h2[1] = __floats2half2_rn(acc2, acc3);
    *(float2*)(qeh + (size_t)n * 256 + h * 32 + d0) = u.f2;
}

// ---------------- fused attention + beta-skip + LN1 + relu ----------------

__global__ __launch_bounds__(256) void attn_kernel(
    const float* __restrict__ efeat,
    const float* __restrict__ We, const float* __restrict__ be,
    const float* __restrict__ q, const __half* __restrict__ qeh,
    const __half2* __restrict__ kvh,
    const float* __restrict__ xr, const float* __restrict__ x,
    const float* __restrict__ Wbeta,
    const float* __restrict__ ln1g, const float* __restrict__ ln1b,
    const int* __restrict__ offsets, const int2* __restrict__ sorted2,
    float* __restrict__ h, float* __restrict__ colsum)
{
    __shared__ float WeS[32][128];
    __shared__ float cs[4][128];
    const int tid = threadIdx.x;
    for (int i = tid; i < 4096; i += 256) ((float*)WeS)[i] = We[i];
    const int lane = tid & 63;
    const int wid = tid >> 6;
    const int f0 = 2 * lane;
    const int l8 = lane & 7;
    const int grp = lane & 56;

    const float be0 = be[f0], be1 = be[f0 + 1];
    const float wbo0 = Wbeta[f0],       wbo1 = Wbeta[f0 + 1];
    const float wbr0 = Wbeta[128 + f0], wbr1 = Wbeta[128 + f0 + 1];
    const float wbd0 = Wbeta[256 + f0], wbd1 = Wbeta[256 + f0 + 1];
    const float lg0 = ln1g[f0], lg1 = ln1g[f0 + 1];
    const float lb0 = ln1b[f0], lb1 = ln1b[f0 + 1];

    cs[wid][f0] = 0.f; cs[wid][f0 + 1] = 0.f;
    __syncthreads();

    const int gwave = blockIdx.x * 4 + wid;
    const int nwave = gridDim.x * 4;

    for (int node = gwave; node < NN; node += nwave) {
        const int beg = offsets[node];
        const int end = offsets[node + 1];
        const float2 qv = *(const float2*)(q + (size_t)node * 128 + f0);
        union { float2 f2; __half2 h2[2]; } uq;
        uq.f2 = *(const float2*)(qeh + (size_t)node * 256 + 4 * lane);
        const float2 qe01 = __half22float2(uq.h2[0]);
        const float2 qe23 = __half22float2(uq.h2[1]);
        const float4 qev = make_float4(qe01.x, qe01.y, qe23.x, qe23.y);
        float qbe = qv.x * be0 + qv.y * be1;
        qbe += __shfl_xor(qbe, 1); qbe += __shfl_xor(qbe, 2); qbe += __shfl_xor(qbe, 4);
        const float qbe25 = qbe * 0.25f;

        float m = -1e30f, s = 0.f, a0 = 0.f, a1 = 0.f;
        float4 wef = f4z();

        if (beg < end) {
            int2 es[8], esn[8];
            {
                int cn = end - beg;
                #pragma unroll
                for (int u = 0; u < 8; ++u) es[u] = sorted2[beg + (u < cn ? u : cn - 1)];
            }
            for (int t = beg; t < end; t += 8) {
                const int cnt = end - t;
                // ---- issue gathers for the current batch ----
                float4 efv[8]; float2 kvraw[8];
                #pragma unroll
                for (int u = 0; u < 8; ++u) {
                    efv[u]   = *(const float4*)(efeat + (size_t)es[u].x * 32 + 4 * l8);
                    kvraw[u] = *(const float2*)(kvh + (size_t)es[u].y * 128 + f0);
                }
                // ---- prefetch next batch's indices under the gather latency ----
                const int tn = t + 8;
                if (tn < end) {
                    int cn = end - tn;
                    #pragma unroll
                    for (int u = 0; u < 8; ++u) esn[u] = sorted2[tn + (u < cn ? u : cn - 1)];
                }
                // ---- logits (parallel across 8 edges) + unpack v ----
                float lgt[8]; float2 vfl[8];
                #pragma unroll
                for (int u = 0; u < 8; ++u) {
                    union { float2 f2; __half2 h2[2]; } uk;
                    uk.f2 = kvraw[u];
                    float2 k0v0 = __half22float2(uk.h2[0]);
                    float2 k1v1 = __half22float2(uk.h2[1]);
                    vfl[u] = make_float2(k0v0.y, k1v1.y);
                    float part = qv.x * k0v0.x + qv.y * k1v1.x
                               + qev.x * efv[u].x + qev.y * efv[u].y
                               + qev.z * efv[u].z + qev.w * efv[u].w;
                    part += __shfl_xor(part, 1);
                    part += __shfl_xor(part, 2);
                    part += __shfl_xor(part, 4);
                    lgt[u] = (u < cnt) ? (part * 0.25f + qbe25) : -1e30f;
                }
                // ---- batch tree combine ----
                float m01 = fmaxf(lgt[0], lgt[1]), m23 = fmaxf(lgt[2], lgt[3]);
                float m45 = fmaxf(lgt[4], lgt[5]), m67 = fmaxf(lgt[6], lgt[7]);
                float bm = fmaxf(fmaxf(m01, m23), fmaxf(m45, m67));
                float p[8];
                #pragma unroll
                for (int u = 0; u < 8; ++u) p[u] = __expf(lgt[u] - bm);
                float bsA = 0.f, bsB = 0.f, b0A = 0.f, b0B = 0.f, b1A = 0.f, b1B = 0.f;
                float4 befA = f4z(), befB = f4z();
                #pragma unroll
                for (int u = 0; u < 8; u += 2) {
                    bsA += p[u];     bsB += p[u + 1];
                    b0A = fmaf(p[u], vfl[u].x, b0A);       b0B = fmaf(p[u + 1], vfl[u + 1].x, b0B);
                    b1A = fmaf(p[u], vfl[u].y, b1A);       b1B = fmaf(p[u + 1], vfl[u + 1].y, b1B);
                    befA.x = fmaf(p[u], efv[u].x, befA.x); befB.x = fmaf(p[u + 1], efv[u + 1].x, befB.x);
                    befA.y = fmaf(p[u], efv[u].y, befA.y); befB.y = fmaf(p[u + 1], efv[u + 1].y, befB.y);
                    befA.z = fmaf(p[u], efv[u].z, befA.z); befB.z = fmaf(p[u + 1], efv[u + 1].z, befB.z);
                    befA.w = fmaf(p[u], efv[u].w, befA.w); befB.w = fmaf(p[u + 1], efv[u + 1].w, befB.w);
                }
                // ---- single merge into running state ----
                const float nm = fmaxf(m, bm);
                const float so = __expf(m - nm);
                const float sn = __expf(bm - nm);
                s  = s  * so + (bsA + bsB) * sn;
                a0 = a0 * so + (b0A + b0B) * sn;
                a1 = a1 * so + (b1A + b1B) * sn;
                wef.x = wef.x * so + (befA.x + befB.x) * sn;
                wef.y = wef.y * so + (befA.y + befB.y) * sn;
                wef.z = wef.z * so + (befA.z + befB.z) * sn;
                wef.w = wef.w * so + (befA.w + befB.w) * sn;
                m = nm;
                #pragma unroll
                for (int u = 0; u < 8; ++u) es[u] = esn[u];
            }
        }

        const float inv = 1.f / (s + 1e-16f);
        float o0 = fmaf(a0, inv, be0);
        float o1 = fmaf(a1, inv, be1);
        float wn0 = wef.x * inv, wn1 = wef.y * inv, wn2 = wef.z * inv, wn3 = wef.w * inv;
        float ew0 = 0.f, ew1 = 0.f;
        #pragma unroll
        for (int l2 = 0; l2 < 8; ++l2) {
            float b0 = __shfl(wn0, grp + l2);
            float b1 = __shfl(wn1, grp + l2);
            float b2 = __shfl(wn2, grp + l2);
            float b3 = __shfl(wn3, grp + l2);
            float2 w0 = *(const float2*)&WeS[4 * l2 + 0][f0];
            float2 w1 = *(const float2*)&WeS[4 * l2 + 1][f0];
            float2 w2 = *(const float2*)&WeS[4 * l2 + 2][f0];
            float2 w3 = *(const float2*)&WeS[4 * l2 + 3][f0];
            ew0 += b0 * w0.x + b1 * w1.x + b2 * w2.x + b3 * w3.x;
            ew1 += b0 * w0.y + b1 * w1.y + b2 * w2.y + b3 * w3.y;
        }
        o0 += ew0; o1 += ew1;
        if (end == beg) { o0 = 0.f; o1 = 0.f; }

        const float2 xrv = *(const float2*)(xr + (size_t)node * 128 + f0);
        float bp = o0 * wbo0 + o1 * wbo1 + xrv.x * wbr0 + xrv.y * wbr1
                 + (o0 - xrv.x) * wbd0 + (o1 - xrv.y) * wbd1;
        #pragma unroll
        for (int msk = 1; msk < 64; msk <<= 1) bp += __shfl_xor(bp, msk);
        const float beta = 1.f / (1.f + __expf(-bp));
        const float2 xv = *(const float2*)(x + (size_t)node * 128 + f0);
        float t0 = beta * xrv.x + (1.f - beta) * o0 + xv.x;
        float t1 = beta * xrv.y + (1.f - beta) * o1 + xv.y;
        float sm = t0 + t1, sq = t0 * t0 + t1 * t1;
        #pragma unroll
        for (int msk = 1; msk < 64; msk <<= 1) { sm += __shfl_xor(sm, msk); sq += __shfl_xor(sq, msk); }
        const float mu = sm * (1.f / 128.f);
        const float var = sq * (1.f / 128.f) - mu * mu;
        const float rstd = rsqrtf(var + 1e-5f);
        const float h0 = fmaxf((t0 - mu) * rstd * lg0 + lb0, 0.f);
        const float h1 = fmaxf((t1 - mu) * rstd * lg1 + lb1, 0.f);
        *(float2*)(h + (size_t)node * 128 + f0) = make_float2(h0, h1);
        cs[wid][f0] += h0; cs[wid][f0 + 1] += h1;
    }
    __syncthreads();
    if (wid == 0) {
        float c0 = cs[0][f0] + cs[1][f0] + cs[2][f0] + cs[3][f0];
        float c1 = cs[0][f0 + 1] + cs[1][f0 + 1] + cs[2][f0 + 1] + cs[3][f0 + 1];
        atomicAdd(&colsum[f0], c0);
        atomicAdd(&colsum[f0 + 1], c1);
    }
}

// ---------------- global context (tiny) ----------------

__global__ __launch_bounds__(128) void gctx_kernel(
    const float* __restrict__ colsum,
    const float* __restrict__ Wr, const float* __restrict__ br,
    const float* __restrict__ Ww, const float* __restrict__ bw,
    const float* __restrict__ Wg, const float* __restrict__ bg,
    float* __restrict__ gc)
{
    __shared__ float hm[128], g[128], gb[128];
    const int f = threadIdx.x;
    hm[f] = colsum[f] * (1.f / (float)NN);
    __syncthreads();
    float a = br[f];
    for (int i = 0; i < 128; ++i) a += hm[i] * Wr[i * 128 + f];
    g[f] = fmaxf(a, 0.f);
    __syncthreads();
    float b = bw[f];
    for (int i = 0; i < 128; ++i) b += g[i] * Ww[i * 128 + f];
    gb[f] = b;
    gc[f] = b;
    __syncthreads();
    float c = bg[f];
    for (int i = 0; i < 128; ++i) c += gb[i] * Wg[(128 + i) * 128 + f];
    gc[128 + f] = c;
}

// ---------------- final: h@Wg[:128] + gate + LN2 fused ----------------

__global__ __launch_bounds__(256) void final_kernel(
    const float* __restrict__ h, const float* __restrict__ Wg,
    const float* __restrict__ gc,
    const float* __restrict__ ln2g, const float* __restrict__ ln2b,
    float* __restrict__ out)
{
    __shared__ float hs[32][128];
    __shared__ float ys[32][128];
    const int tid = threadIdx.x;
    const int row0 = blockIdx.x * 32;
    for (int i = tid; i < 1024; i += 256) {
        int r = i >> 5, c4 = i & 31;
        int gr = row0 + r;
        float4 val = f4z();
        if (gr < NN) val = ((const float4*)(h + (size_t)gr * 128))[c4];
        ((float4*)hs[r])[c4] = val;
    }
    __syncthreads();
    const int cg = tid & 31;
    const int rg = tid >> 5;
    float4 a[4];
    #pragma unroll
    for (int r = 0; r < 4; ++r) a[r] = f4z();
    #pragma unroll 2
    for (int kk = 0; kk < 128; ++kk) {
        float4 w4 = ((const float4*)(Wg + kk * 128))[cg];
        #pragma unroll
        for (int r = 0; r < 4; ++r) {
            float xv = hs[4 * rg + r][kk];
            a[r].x += xv * w4.x; a[r].y += xv * w4.y; a[r].z += xv * w4.z; a[r].w += xv * w4.w;
        }
    }
    const float4 gb = ((const float4*)gc)[cg];
    const float4 c2 = ((const float4*)(gc + 128))[cg];
    #pragma unroll
    for (int r = 0; r < 4; ++r) {
        int row = 4 * rg + r;
        float4 hv = ((float4*)hs[row])[cg];
        float4 y;
        float gx;
        gx = 1.f / (1.f + __expf(-(a[r].x + c2.x))); y.x = hv.x + gx * gb.x;
        gx = 1.f / (1.f + __expf(-(a[r].y + c2.y))); y.y = hv.y + gx * gb.y;
        gx = 1.f / (1.f + __expf(-(a[r].z + c2.z))); y.z = hv.z + gx * gb.z;
        gx = 1.f / (1.f + __expf(-(a[r].w + c2.w))); y.w = hv.w + gx * gb.w;
        ((float4*)ys[row])[cg] = y;
    }
    __syncthreads();
    const int lane = tid & 63;
    const int wid = tid >> 6;
    const int f0 = 2 * lane;
    const float lg0 = ln2g[f0], lg1 = ln2g[f0 + 1];
    const float lb0 = ln2b[f0], lb1 = ln2b[f0 + 1];
    for (int rr = 0; rr < 8; ++rr) {
        int row = wid * 8 + rr;
        int gr = row0 + row;
        if (gr >= NN) continue;
        float y0 = ys[row][f0], y1 = ys[row][f0 + 1];
        float sm = y0 + y1, sq = y0 * y0 + y1 * y1;
        #pragma unroll
        for (int msk = 1; msk < 64; msk <<= 1) { sm += __shfl_xor(sm, msk); sq += __shfl_xor(sq, msk); }
        float mu = sm * (1.f / 128.f);
        float var = sq * (1.f / 128.f) - mu * mu;
        float rstd = rsqrtf(var + 1e-5f);
        float o0 = (y0 - mu) * rstd * lg0 + lb0;
        float o1 = (y1 - mu) * rstd * lg1 + lb1;
        *(float2*)(out + (size_t)gr * 128 + f0) = make_float2(o0, o1);
    }
}

// ---------------- launch ----------------

extern "C" void kernel_launch(void* const* d_in, const int* in_sizes, int n_in,
                              void* d_out, int out_size, void* d_ws, size_t ws_size,
                              hipStream_t stream)
{
    const float* x    = (const float*)d_in[0];
    const int*   ei   = (const int*)d_in[1];
    const float* ef   = (const float*)d_in[2];
    const float* Wq   = (const float*)d_in[3];
    const float* bq   = (const float*)d_in[4];
    const float* Wk   = (const float*)d_in[5];
    const float* bk   = (const float*)d_in[6];
    const float* Wv   = (const float*)d_in[7];
    const float* bv   = (const float*)d_in[8];
    const float* We   = (const float*)d_in[9];
    const float* be   = (const float*)d_in[10];
    const float* Wsk  = (const float*)d_in[11];
    const float* bsk  = (const float*)d_in[12];
    const float* Wbeta= (const float*)d_in[13];
    const float* g1   = (const float*)d_in[14];
    const float* b1   = (const float*)d_in[15];
    const float* Wr   = (const float*)d_in[16];
    const float* br   = (const float*)d_in[17];
    const float* Ww   = (const float*)d_in[18];
    const float* bw   = (const float*)d_in[19];
    const float* Wg   = (const float*)d_in[20];
    const float* bg   = (const float*)d_in[21];
    const float* g2   = (const float*)d_in[22];
    const float* b2   = (const float*)d_in[23];
    float* out = (float*)d_out;

    const size_t NF = (size_t)NN * 128;
    float* q      = (float*)d_ws;
    float* xr     = q + NF;
    float* h      = xr + NF;
    __half2* kvh  = (__half2*)(h + NF);       // NN*128 half2 = NF floats
    __half* qeh   = (__half*)(kvh + NF);      // NN*256 half  = NF floats
    float* colsum = (float*)(qeh + (size_t)NN * 256);
    float* gc     = colsum + 128;             // 256 floats
    int* counts   = (int*)(gc + 256);
    int* offsets  = counts + NN;              // NN+2 (pad)
    int* cursor   = offsets + NN + 2;
    int2* sorted2 = (int2*)(cursor + NN);     // EE int2

    hipMemsetAsync(counts, 0, NN * sizeof(int), stream);
    hipMemsetAsync(colsum, 0, 128 * sizeof(float), stream);

    hist_kernel<<<2048, 256, 0, stream>>>(ei, counts);
    scan_kernel<<<1, 1024, 0, stream>>>(counts, offsets, cursor);
    scatter_kernel<<<2048, 256, 0, stream>>>(ei, cursor, sorted2);
    proj_kernel<<<(NN + 31) / 32, 256, 0, stream>>>(x, Wq, bq, Wk, bk, Wv, bv, Wsk, bsk, q, kvh, xr);
    qe_small<<<(NN * 64 + 255) / 256, 256, 0, stream>>>(q, We, qeh);
    attn_kernel<<<2048, 256, 0, stream>>>(ef, We, be, q, qeh, kvh, xr, x, Wbeta, g1, b1,
                                          offsets, sorted2, h, colsum);
    gctx_kernel<<<1, 128, 0, stream>>>(colsum, Wr, br, Ww, bw, Wg, bg, gc);
    final_kernel<<<(NN + 31) / 32, 256, 0, stream>>>(h, Wg, gc, g2, b2, out);
}